// Round 4
// baseline (231.580 us; speedup 1.0000x reference)
//
#include <hip/hip_runtime.h>
#include <hip/hip_bf16.h>

typedef unsigned short u16;

#define BATCH 8
#define CIN 512
#define COUT 512
#define SDIM 512
#define RES 64
#define PIX (RES * RES)          // 4096
#define NKT 72                   // K-tiles of 64: 9 taps * 8 cin-blocks

__device__ __constant__ static const float kAffScale  = 0.04419417382415922f;   // 1/sqrt(512)
__device__ __constant__ static const float kConvScale = 0.014731391274719742f;  // 1/sqrt(512*9)
__device__ __constant__ static const float kGain      = 1.4142135623730951f;    // sqrt(2)

typedef __bf16 bf16x8 __attribute__((ext_vector_type(8)));
typedef float  f32x4  __attribute__((ext_vector_type(4)));

// ---------------------------------------------------------------------------
// Kernel 1: style[b][c] = (w[b] . affine_w[c]) * AFF_SCALE + affine_b[c]
// ---------------------------------------------------------------------------
__global__ void style_k(const float* __restrict__ w, const float* __restrict__ aw,
                        const float* __restrict__ ab, float* __restrict__ style,
                        float* __restrict__ zbuf) {
  int tid = blockIdx.x * 256 + threadIdx.x;      // 0..4095
  if (blockIdx.x == 0 && threadIdx.x < 64) zbuf[threadIdx.x] = 0.0f;
  int b = tid >> 9, c = tid & 511;
  const float* wp = w + b * SDIM;
  const float* ap = aw + c * SDIM;
  float s = 0.0f;
  for (int k = 0; k < SDIM; ++k) s += wp[k] * ap[k];
  style[tid] = s * kAffScale + ab[c];
}

// ---------------------------------------------------------------------------
// Kernel 2: cw2[o][i] = sum_t conv_w[o][i][t]^2
// ---------------------------------------------------------------------------
__global__ void cw2_k(const float* __restrict__ cw, float* __restrict__ cw2) {
  int tid = blockIdx.x * 256 + threadIdx.x;      // o*512+i
  const float* p = cw + tid * 9;
  float s = 0.0f;
  #pragma unroll
  for (int t = 0; t < 9; ++t) { float v = p[t]; s += v * v; }
  cw2[tid] = s;
}

// ---------------------------------------------------------------------------
// Kernel 3: fac[b][o] = CONV_SCALE * rsqrt(CONV_SCALE^2 * sum_i style^2*cw2 + 1e-8)
// ---------------------------------------------------------------------------
__global__ void fac_k(const float* __restrict__ style, const float* __restrict__ cw2,
                      float* __restrict__ fac) {
  int wid  = blockIdx.x * 4 + (threadIdx.x >> 6); // 0..4095
  int lane = threadIdx.x & 63;
  int b = wid >> 9, o = wid & 511;
  const float* st = style + b * CIN;
  const float* c2 = cw2 + o * CIN;
  float s = 0.0f;
  for (int i = lane; i < CIN; i += 64) { float sv = st[i]; s += sv * sv * c2[i]; }
  #pragma unroll
  for (int off = 32; off; off >>= 1) s += __shfl_xor(s, off);
  if (lane == 0) {
    float d = rsqrtf(s * kConvScale * kConvScale + 1e-8f);
    fac[wid] = d * kConvScale;
  }
}

// ---------------------------------------------------------------------------
// Kernel 4: wbt[(tap*16+sl)][o][j] = bf16(conv_w[o][sl*32+j][tap])
// Panel layout: each (tap, cin-slice-of-32) is a contiguous [512][32] u16 slab
// so gemm A-staging is fully linear.
// ---------------------------------------------------------------------------
__global__ void wcast_k(const float* __restrict__ cw, u16* __restrict__ wbt) {
  int tid = blockIdx.x * 256 + threadIdx.x;      // o*512 + i
  int o = tid >> 9, i = tid & 511;
  const float* p = cw + tid * 9;
  #pragma unroll
  for (int t = 0; t < 9; ++t) {
    __hip_bfloat16 h = __float2bfloat16(p[t]);
    wbt[((size_t)(t * 16 + (i >> 5)) * 512 + o) * 32 + (i & 31)] = *(u16*)&h;
  }
}

// ---------------------------------------------------------------------------
// Kernel 5: xst[(b*16+sl)][pix][j] = bf16(x[b][sl*32+j][pix] * style)
// Panel layout: each (b, cin-slice-of-32) is a contiguous [4096][32] u16 slab
// so gemm B-staging is linear and the 3x3 halo shift is a constant offset.
// ---------------------------------------------------------------------------
__global__ void modx_k(const float* __restrict__ x, const float* __restrict__ style,
                       u16* __restrict__ xst) {
  __shared__ float t[64][65];
  int b  = blockIdx.z;
  int it = blockIdx.y * 64;                      // cin tile base
  int pt = blockIdx.x * 64;                      // pixel tile base
  int tp = threadIdx.x & 63;
  int tr = threadIdx.x >> 6;                     // 0..3
  for (int r = tr; r < 64; r += 4) {
    int i = it + r;
    t[r][tp] = x[(b * CIN + i) * PIX + pt + tp] * style[b * CIN + i];
  }
  __syncthreads();
  int i = it + tp;
  size_t base = ((size_t)(b * 16 + (i >> 5)) * PIX) * 32 + (i & 31);
  for (int r = tr; r < 64; r += 4) {
    __hip_bfloat16 h = __float2bfloat16(t[tp][r]);
    xst[base + (size_t)(pt + r) * 32] = *(u16*)&h;
  }
}

// ---------------------------------------------------------------------------
// Kernel 6: implicit-GEMM conv, 8-phase schedule (round-3 structure) with
//  (a) compiler-managed fine-grained lgkmcnt (no drain-pin before MFMA),
//  (b) fully-coalesced panel staging (linear per-thread source addresses).
// BM=BN=256, BK=64 (2 K-slices of 32). 8 waves (2M x 4N), wave out 128x64.
// LDS: 2 dbuf x [2 kh][256 rows][32 elems], slot swizzle (c&3)^((row>>1)&3).
// vmcnt(8) twice per K-tile (never 0 in main loop).
// ---------------------------------------------------------------------------
__launch_bounds__(512, 2)
__global__ void gemm_k(const u16* __restrict__ wbt, const u16* __restrict__ xst,
                       const float* __restrict__ fac, const float* __restrict__ noise,
                       const float* __restrict__ nscale_p, const float* __restrict__ bias,
                       const float* __restrict__ zbuf, float* __restrict__ y) {
  __shared__ __align__(16) u16 Abuf[2][16384];   // [dbuf][kh*8192 + row*32 + slot*8]
  __shared__ __align__(16) u16 Bbuf[2][16384];

  const int tid = threadIdx.x;
  const int bid = blockIdx.x;                    // 0..255
  const int swz = (bid & 7) * 32 + (bid >> 3);   // XCD-chunked (256 % 8 == 0)
  const int mt = swz >> 7;                       // 0..1   cout tile
  const int nt = swz & 127;                      // 0..127 pixel tile
  const int b  = nt >> 4;                        // image
  const int pimg  = (nt & 15) * 256;             // pixel base within image
  const int hbase = pimg >> 6;                   // image row base

  const int lane = tid & 63;
  const int wv = tid >> 6;                       // 0..7
  const int wm = wv >> 2;                        // 0..1  (128 out-rows)
  const int wn = wv & 3;                         // 0..3  (64 out-cols)
  const int l15 = lane & 15, l4 = lane >> 4;
  const int slot = (l4 ^ ((l15 >> 1) & 3)) * 8;  // swizzled 16B slot (u16 units)

  // ---- staging per-thread constants: chunk c = p*512+tid, row=c>>2, slot=c&3
  const int sgE = ((tid & 3) ^ ((tid >> 3) & 3)) << 3;  // swizzled source elem offset
  int aoff[2], boff[2], hr[2], wc[2];
  #pragma unroll
  for (int p = 0; p < 2; ++p) {
    int row = (p * 512 + tid) >> 2;              // 0..255
    aoff[p] = (mt * 256 + row) * 32 + sgE;       // elem offset within A panel
    boff[p] = (pimg + row) * 32 + sgE;           // elem offset within B panel
    hr[p] = hbase + (row >> 6);
    wc[p] = row & 63;
  }

  // stage one K-slice quantum (2 x global_load_lds 16B per thread)
  auto stA = [&](int ktx, int kh) {
    if (ktx >= NKT) ktx -= NKT;
    const int d = ktx & 1;
    const u16* pan = wbt + ((size_t)((ktx >> 3) * 16 + ((ktx & 7) << 1) + kh) << 14);
    #pragma unroll
    for (int p = 0; p < 2; ++p) {
      const u16* src = pan + aoff[p];
      __builtin_amdgcn_global_load_lds(
          (const __attribute__((address_space(1))) void*)src,
          (__attribute__((address_space(3))) void*)(&Abuf[d][kh * 8192 + (p * 512 + tid) * 8]),
          16, 0, 0);
    }
  };
  auto stB = [&](int ktx, int kh) {
    if (ktx >= NKT) ktx -= NKT;
    const int tap = ktx >> 3;
    const int dy  = tap < 3 ? -1 : (tap < 6 ? 0 : 1);
    const int dx  = (tap - (tap < 3 ? 0 : (tap < 6 ? 3 : 6))) - 1;
    const int d   = ktx & 1;
    const u16* pan = xst + ((size_t)(b * 16 + ((ktx & 7) << 1) + kh) << 17);
    const int shiftE = (dy * 64 + dx) * 32;
    #pragma unroll
    for (int p = 0; p < 2; ++p) {
      int hh = hr[p] + dy, ww = wc[p] + dx;
      const u16* src = ((unsigned)hh < 64u && (unsigned)ww < 64u)
          ? pan + (boff[p] + shiftE) : (const u16*)zbuf;
      __builtin_amdgcn_global_load_lds(
          (const __attribute__((address_space(1))) void*)src,
          (__attribute__((address_space(3))) void*)(&Bbuf[d][kh * 8192 + (p * 512 + tid) * 8]),
          16, 0, 0);
    }
  };

  f32x4 acc[8][4];
  #pragma unroll
  for (int i = 0; i < 8; ++i)
    #pragma unroll
    for (int j = 0; j < 4; ++j) acc[i][j] = (f32x4){0.f, 0.f, 0.f, 0.f};

  // Prologue: kt0 full tile + kt1 kh0; 12 loads in flight, drain 4.
  stA(0, 0); stB(0, 0); stA(0, 1); stB(0, 1); stA(1, 0); stB(1, 0);
  asm volatile("s_waitcnt vmcnt(8)" ::: "memory");   // kt0 kh0 (A+B) landed
  __builtin_amdgcn_s_barrier();

#define LDA(mi, kh) (*(const bf16x8*)&Ab[(kh) * 8192 + (wm * 128 + (mi) * 16 + l15) * 32 + slot])
#define LDB(ni, kh) (*(const bf16x8*)&Bb[(kh) * 8192 + (wn * 64 + (ni) * 16 + l15) * 32 + slot])

  for (int kt = 0; kt < NKT; ++kt) {
    const u16* Ab = &Abuf[kt & 1][0];
    const u16* Bb = &Bbuf[kt & 1][0];
    bf16x8 bfr[4], af[4];

    // ---- phase 0: kh0 mi0-3 ----
    #pragma unroll
    for (int ni = 0; ni < 4; ++ni) bfr[ni] = LDB(ni, 0);
    #pragma unroll
    for (int j = 0; j < 4; ++j) af[j] = LDA(j, 0);
    stA(kt + 1, 1);
    __builtin_amdgcn_s_barrier();
    __builtin_amdgcn_s_setprio(1);
    #pragma unroll
    for (int j = 0; j < 4; ++j)
      #pragma unroll
      for (int ni = 0; ni < 4; ++ni)
        acc[j][ni] = __builtin_amdgcn_mfma_f32_16x16x32_bf16(af[j], bfr[ni], acc[j][ni], 0, 0, 0);
    __builtin_amdgcn_s_setprio(0);
    __builtin_amdgcn_s_barrier();

    // ---- phase 1: kh0 mi4-7 ----
    #pragma unroll
    for (int j = 0; j < 4; ++j) af[j] = LDA(4 + j, 0);
    stB(kt + 1, 1);
    __builtin_amdgcn_s_barrier();
    __builtin_amdgcn_s_setprio(1);
    #pragma unroll
    for (int j = 0; j < 4; ++j)
      #pragma unroll
      for (int ni = 0; ni < 4; ++ni)
        acc[4 + j][ni] = __builtin_amdgcn_mfma_f32_16x16x32_bf16(af[j], bfr[ni], acc[4 + j][ni], 0, 0, 0);
    __builtin_amdgcn_s_setprio(0);
    asm volatile("s_waitcnt vmcnt(8)" ::: "memory");   // kt's kh1 slices landed
    __builtin_amdgcn_s_barrier();

    // ---- phase 2: kh1 mi0-3 ----
    #pragma unroll
    for (int ni = 0; ni < 4; ++ni) bfr[ni] = LDB(ni, 1);
    #pragma unroll
    for (int j = 0; j < 4; ++j) af[j] = LDA(j, 1);
    stA(kt + 2, 0);
    __builtin_amdgcn_s_barrier();
    __builtin_amdgcn_s_setprio(1);
    #pragma unroll
    for (int j = 0; j < 4; ++j)
      #pragma unroll
      for (int ni = 0; ni < 4; ++ni)
        acc[j][ni] = __builtin_amdgcn_mfma_f32_16x16x32_bf16(af[j], bfr[ni], acc[j][ni], 0, 0, 0);
    __builtin_amdgcn_s_setprio(0);
    __builtin_amdgcn_s_barrier();

    // ---- phase 3: kh1 mi4-7 ----
    #pragma unroll
    for (int j = 0; j < 4; ++j) af[j] = LDA(4 + j, 1);
    stB(kt + 2, 0);
    __builtin_amdgcn_s_barrier();
    __builtin_amdgcn_s_setprio(1);
    #pragma unroll
    for (int j = 0; j < 4; ++j)
      #pragma unroll
      for (int ni = 0; ni < 4; ++ni)
        acc[4 + j][ni] = __builtin_amdgcn_mfma_f32_16x16x32_bf16(af[j], bfr[ni], acc[4 + j][ni], 0, 0, 0);
    __builtin_amdgcn_s_setprio(0);
    asm volatile("s_waitcnt vmcnt(8)" ::: "memory");   // kt+1's kh0 slices landed
    __builtin_amdgcn_s_barrier();
  }
#undef LDA
#undef LDB

  // Epilogue: y = lrelu(acc*fac + noise*nscale + bias) * sqrt(2)
  const float ns = nscale_p[0];
  float nz[4];
  #pragma unroll
  for (int ni = 0; ni < 4; ++ni) {
    int pix = pimg + wn * 64 + ni * 16 + l15;
    nz[ni] = noise[b * PIX + pix] * ns;
  }
  #pragma unroll
  for (int mi = 0; mi < 8; ++mi) {
    int o = mt * 256 + wm * 128 + mi * 16 + l4 * 4;
    f32x4 fv = *(const f32x4*)&fac[b * COUT + o];
    f32x4 bv = *(const f32x4*)&bias[o];
    #pragma unroll
    for (int r = 0; r < 4; ++r) {
      float* yp = y + (size_t)(b * COUT + o + r) * PIX + pimg + wn * 64 + l15;
      #pragma unroll
      for (int ni = 0; ni < 4; ++ni) {
        float v = acc[mi][ni][r] * fv[r] + nz[ni] + bv[r];
        v = (v > 0.0f ? v : 0.2f * v) * kGain;
        yp[ni * 16] = v;
      }
    }
  }
}

// ---------------------------------------------------------------------------
extern "C" void kernel_launch(void* const* d_in, const int* in_sizes, int n_in,
                              void* d_out, int out_size, void* d_ws, size_t ws_size,
                              hipStream_t stream) {
  const float* x      = (const float*)d_in[0];
  const float* w      = (const float*)d_in[1];
  const float* noise  = (const float*)d_in[2];
  const float* aff_w  = (const float*)d_in[3];
  const float* aff_b  = (const float*)d_in[4];
  const float* conv_w = (const float*)d_in[5];
  const float* nscale = (const float*)d_in[6];
  const float* bias   = (const float*)d_in[7];
  float* y = (float*)d_out;

  char* ws = (char*)d_ws;
  float* style = (float*)(ws);                          // 16 KB
  float* fac   = (float*)(ws + 16384);                  // 16 KB
  float* cw2   = (float*)(ws + 32768);                  // 1 MB
  float* zbuf  = (float*)(ws + 1081344);                // 256 B zeros
  u16*   wbt   = (u16*)(ws + 1081600);                  // 4.5 MB panels
  u16*   xst   = (u16*)(ws + 5800192);                  // 32 MB panels

  style_k<<<16, 256, 0, stream>>>(w, aff_w, aff_b, style, zbuf);
  cw2_k<<<1024, 256, 0, stream>>>(conv_w, cw2);
  fac_k<<<1024, 256, 0, stream>>>(style, cw2, fac);
  wcast_k<<<1024, 256, 0, stream>>>(conv_w, wbt);
  modx_k<<<dim3(64, 8, 8), 256, 0, stream>>>(x, style, xst);
  gemm_k<<<256, 512, 0, stream>>>(wbt, xst, fac, noise, nscale, bias, zbuf, y);
}

// Round 5
// 217.095 us; speedup vs baseline: 1.0667x; 1.0667x over previous
//
#include <hip/hip_runtime.h>
#include <hip/hip_bf16.h>

typedef unsigned short u16;

#define BATCH 8
#define CIN 512
#define COUT 512
#define SDIM 512
#define RES 64
#define PIX (RES * RES)          // 4096
#define NKT 72                   // K-tiles of 64: 9 taps * 8 cin-blocks

__device__ __constant__ static const float kAffScale  = 0.04419417382415922f;   // 1/sqrt(512)
__device__ __constant__ static const float kConvScale = 0.014731391274719742f;  // 1/sqrt(512*9)
__device__ __constant__ static const float kGain      = 1.4142135623730951f;    // sqrt(2)

typedef __bf16 bf16x8 __attribute__((ext_vector_type(8)));
typedef float  f32x4  __attribute__((ext_vector_type(4)));

// ---------------------------------------------------------------------------
// Kernel 1: style[b][c] = (w[b] . affine_w[c]) * AFF_SCALE + affine_b[c]
// ---------------------------------------------------------------------------
__global__ void style_k(const float* __restrict__ w, const float* __restrict__ aw,
                        const float* __restrict__ ab, float* __restrict__ style,
                        float* __restrict__ zbuf) {
  int tid = blockIdx.x * 256 + threadIdx.x;      // 0..4095
  if (blockIdx.x == 0 && threadIdx.x < 64) zbuf[threadIdx.x] = 0.0f;
  int b = tid >> 9, c = tid & 511;
  const float* wp = w + b * SDIM;
  const float* ap = aw + c * SDIM;
  float s = 0.0f;
  for (int k = 0; k < SDIM; ++k) s += wp[k] * ap[k];
  style[tid] = s * kAffScale + ab[c];
}

// ---------------------------------------------------------------------------
// Kernel 2: cw2[o][i] = sum_t conv_w[o][i][t]^2
// ---------------------------------------------------------------------------
__global__ void cw2_k(const float* __restrict__ cw, float* __restrict__ cw2) {
  int tid = blockIdx.x * 256 + threadIdx.x;      // o*512+i
  const float* p = cw + tid * 9;
  float s = 0.0f;
  #pragma unroll
  for (int t = 0; t < 9; ++t) { float v = p[t]; s += v * v; }
  cw2[tid] = s;
}

// ---------------------------------------------------------------------------
// Kernel 3: fac[b][o] = CONV_SCALE * rsqrt(CONV_SCALE^2 * sum_i style^2*cw2 + 1e-8)
// ---------------------------------------------------------------------------
__global__ void fac_k(const float* __restrict__ style, const float* __restrict__ cw2,
                      float* __restrict__ fac) {
  int wid  = blockIdx.x * 4 + (threadIdx.x >> 6); // 0..4095
  int lane = threadIdx.x & 63;
  int b = wid >> 9, o = wid & 511;
  const float* st = style + b * CIN;
  const float* c2 = cw2 + o * CIN;
  float s = 0.0f;
  for (int i = lane; i < CIN; i += 64) { float sv = st[i]; s += sv * sv * c2[i]; }
  #pragma unroll
  for (int off = 32; off; off >>= 1) s += __shfl_xor(s, off);
  if (lane == 0) {
    float d = rsqrtf(s * kConvScale * kConvScale + 1e-8f);
    fac[wid] = d * kConvScale;
  }
}

// ---------------------------------------------------------------------------
// Kernel 4: wbt[(tap*16+sl)][o][j] = bf16(conv_w[o][sl*32+j][tap])
// ---------------------------------------------------------------------------
__global__ void wcast_k(const float* __restrict__ cw, u16* __restrict__ wbt) {
  int tid = blockIdx.x * 256 + threadIdx.x;      // o*512 + i
  int o = tid >> 9, i = tid & 511;
  const float* p = cw + tid * 9;
  #pragma unroll
  for (int t = 0; t < 9; ++t) {
    __hip_bfloat16 h = __float2bfloat16(p[t]);
    wbt[((size_t)(t * 16 + (i >> 5)) * 512 + o) * 32 + (i & 31)] = *(u16*)&h;
  }
}

// ---------------------------------------------------------------------------
// Kernel 5: xst[(b*16+sl)][pix][j] = bf16(x[b][sl*32+j][pix] * style)
// ---------------------------------------------------------------------------
__global__ void modx_k(const float* __restrict__ x, const float* __restrict__ style,
                       u16* __restrict__ xst) {
  __shared__ float t[64][65];
  int b  = blockIdx.z;
  int it = blockIdx.y * 64;                      // cin tile base
  int pt = blockIdx.x * 64;                      // pixel tile base
  int tp = threadIdx.x & 63;
  int tr = threadIdx.x >> 6;                     // 0..3
  for (int r = tr; r < 64; r += 4) {
    int i = it + r;
    t[r][tp] = x[(b * CIN + i) * PIX + pt + tp] * style[b * CIN + i];
  }
  __syncthreads();
  int i = it + tp;
  size_t base = ((size_t)(b * 16 + (i >> 5)) * PIX) * 32 + (i & 31);
  for (int r = tr; r < 64; r += 4) {
    __hip_bfloat16 h = __float2bfloat16(t[tp][r]);
    xst[base + (size_t)(pt + r) * 32] = *(u16*)&h;
  }
}

// ---------------------------------------------------------------------------
// Kernel 6: implicit-GEMM conv, 8-phase schedule with CROSS-PHASE REGISTER
// PREFETCH: each phase issues next phase's ds_reads, so the post-barrier
// lgkmcnt is counted (4/8), never a full drain; MFMA overlaps this phase's
// LDS traffic. vmcnt(6)+barrier at end of A-phases publishes DMA completion
// before the B-phase reads the new slice. One barrier per phase.
// BM=BN=256, BK=64 (2 kh-slices), 8 waves (2Mx4N), wave out 128x64.
// ---------------------------------------------------------------------------
__launch_bounds__(512, 2)
__global__ void gemm_k(const u16* __restrict__ wbt, const u16* __restrict__ xst,
                       const float* __restrict__ fac, const float* __restrict__ noise,
                       const float* __restrict__ nscale_p, const float* __restrict__ bias,
                       const float* __restrict__ zbuf, float* __restrict__ y) {
  __shared__ __align__(16) u16 Abuf[2][16384];   // [dbuf][kh*8192 + row*32 + slot*8]
  __shared__ __align__(16) u16 Bbuf[2][16384];

  const int tid = threadIdx.x;
  const int bid = blockIdx.x;                    // 0..255
  const int swz = (bid & 7) * 32 + (bid >> 3);   // XCD-chunked (256 % 8 == 0)
  const int mt = swz >> 7;                       // 0..1   cout tile
  const int nt = swz & 127;                      // 0..127 pixel tile
  const int b  = nt >> 4;                        // image
  const int pimg  = (nt & 15) * 256;             // pixel base within image
  const int hbase = pimg >> 6;                   // image row base

  const int lane = tid & 63;
  const int wv = tid >> 6;                       // 0..7
  const int wm = wv >> 2;                        // 0..1  (128 out-rows)
  const int wn = wv & 3;                         // 0..3  (64 out-cols)
  const int l15 = lane & 15, l4 = lane >> 4;
  const int slot = (l4 ^ ((l15 >> 1) & 3)) * 8;  // swizzled 16B slot (u16 units)

  // ---- staging per-thread constants: chunk c = p*512+tid, row=c>>2, slot=c&3
  const int sgE = ((tid & 3) ^ ((tid >> 3) & 3)) << 3;  // swizzled source elem offset
  int aoff[2], boff[2], hr[2], wc[2];
  #pragma unroll
  for (int p = 0; p < 2; ++p) {
    int row = (p * 512 + tid) >> 2;              // 0..255
    aoff[p] = (mt * 256 + row) * 32 + sgE;       // elem offset within A panel
    boff[p] = (pimg + row) * 32 + sgE;           // elem offset within B panel
    hr[p] = hbase + (row >> 6);
    wc[p] = row & 63;
  }

  auto stA = [&](int ktx, int kh) {
    if (ktx >= NKT) ktx -= NKT;
    const int d = ktx & 1;
    const u16* pan = wbt + ((size_t)((ktx >> 3) * 16 + ((ktx & 7) << 1) + kh) << 14);
    #pragma unroll
    for (int p = 0; p < 2; ++p) {
      const u16* src = pan + aoff[p];
      __builtin_amdgcn_global_load_lds(
          (const __attribute__((address_space(1))) void*)src,
          (__attribute__((address_space(3))) void*)(&Abuf[d][kh * 8192 + (p * 512 + tid) * 8]),
          16, 0, 0);
    }
  };
  auto stB = [&](int ktx, int kh) {
    if (ktx >= NKT) ktx -= NKT;
    const int tap = ktx >> 3;
    const int dy  = tap < 3 ? -1 : (tap < 6 ? 0 : 1);
    const int dx  = (tap - (tap < 3 ? 0 : (tap < 6 ? 3 : 6))) - 1;
    const int d   = ktx & 1;
    const u16* pan = xst + ((size_t)(b * 16 + ((ktx & 7) << 1) + kh) << 17);
    const int shiftE = (dy * 64 + dx) * 32;
    #pragma unroll
    for (int p = 0; p < 2; ++p) {
      int hh = hr[p] + dy, ww = wc[p] + dx;
      const u16* src = ((unsigned)hh < 64u && (unsigned)ww < 64u)
          ? pan + (boff[p] + shiftE) : (const u16*)zbuf;
      __builtin_amdgcn_global_load_lds(
          (const __attribute__((address_space(1))) void*)src,
          (__attribute__((address_space(3))) void*)(&Bbuf[d][kh * 8192 + (p * 512 + tid) * 8]),
          16, 0, 0);
    }
  };

  f32x4 acc[8][4];
  #pragma unroll
  for (int i = 0; i < 8; ++i)
    #pragma unroll
    for (int j = 0; j < 4; ++j) acc[i][j] = (f32x4){0.f, 0.f, 0.f, 0.f};

#define LDAp(base, mi, kh) (*(const bf16x8*)&(base)[(kh) * 8192 + (wm * 128 + (mi) * 16 + l15) * 32 + slot])
#define LDBp(base, ni, kh) (*(const bf16x8*)&(base)[(kh) * 8192 + (wn * 64 + (ni) * 16 + l15) * 32 + slot])

  // Prologue: 6 DMA quanta; slice(0,kh0) valid after vmcnt(8)+barrier.
  stA(0, 0); stB(0, 0); stA(0, 1); stB(0, 1); stA(1, 0); stB(1, 0);
  asm volatile("s_waitcnt vmcnt(8)" ::: "memory");
  __builtin_amdgcn_s_barrier();

  bf16x8 af03[4], af47[4], bfr0[4], bfr1[4];
  {
    const u16* Ab = &Abuf[0][0];
    const u16* Bb = &Bbuf[0][0];
    #pragma unroll
    for (int ni = 0; ni < 4; ++ni) bfr0[ni] = LDBp(Bb, ni, 0);
    #pragma unroll
    for (int j = 0; j < 4; ++j) af03[j] = LDAp(Ab, j, 0);
  }

  for (int kt = 0; kt < NKT; ++kt) {
    const u16* Ab  = &Abuf[kt & 1][0];
    const u16* Bb  = &Bbuf[kt & 1][0];
    const u16* AbN = &Abuf[(kt + 1) & 1][0];
    const u16* BbN = &Bbuf[(kt + 1) & 1][0];

    // ---- phase A0: MFMA acc[0-3] (kh0: af03 x bfr0); prefetch af47(kh0) ----
    #pragma unroll
    for (int j = 0; j < 4; ++j) af47[j] = LDAp(Ab, 4 + j, 0);
    stA(kt + 1, 1);
    asm volatile("s_waitcnt lgkmcnt(4)" ::: "memory");
    __builtin_amdgcn_sched_barrier(0);
    __builtin_amdgcn_s_setprio(1);
    #pragma unroll
    for (int j = 0; j < 4; ++j)
      #pragma unroll
      for (int ni = 0; ni < 4; ++ni)
        acc[j][ni] = __builtin_amdgcn_mfma_f32_16x16x32_bf16(af03[j], bfr0[ni], acc[j][ni], 0, 0, 0);
    __builtin_amdgcn_s_setprio(0);
    asm volatile("s_waitcnt vmcnt(6)" ::: "memory");   // (kt,kh1) DMA landed
    __builtin_amdgcn_s_barrier();                      // publish across waves

    // ---- phase B0: prefetch bfr1,af03(kh1); MFMA acc[4-7] (af47 x bfr0) ----
    #pragma unroll
    for (int ni = 0; ni < 4; ++ni) bfr1[ni] = LDBp(Bb, ni, 1);
    #pragma unroll
    for (int j = 0; j < 4; ++j) af03[j] = LDAp(Ab, j, 1);
    stB(kt + 1, 1);
    asm volatile("s_waitcnt lgkmcnt(8)" ::: "memory");
    __builtin_amdgcn_sched_barrier(0);
    __builtin_amdgcn_s_setprio(1);
    #pragma unroll
    for (int j = 0; j < 4; ++j)
      #pragma unroll
      for (int ni = 0; ni < 4; ++ni)
        acc[4 + j][ni] = __builtin_amdgcn_mfma_f32_16x16x32_bf16(af47[j], bfr0[ni], acc[4 + j][ni], 0, 0, 0);
    __builtin_amdgcn_s_setprio(0);
    __builtin_amdgcn_s_barrier();

    // ---- phase A1: MFMA acc[0-3] (kh1: af03 x bfr1); prefetch af47(kh1) ----
    #pragma unroll
    for (int j = 0; j < 4; ++j) af47[j] = LDAp(Ab, 4 + j, 1);
    stA(kt + 2, 0);
    asm volatile("s_waitcnt lgkmcnt(4)" ::: "memory");
    __builtin_amdgcn_sched_barrier(0);
    __builtin_amdgcn_s_setprio(1);
    #pragma unroll
    for (int j = 0; j < 4; ++j)
      #pragma unroll
      for (int ni = 0; ni < 4; ++ni)
        acc[j][ni] = __builtin_amdgcn_mfma_f32_16x16x32_bf16(af03[j], bfr1[ni], acc[j][ni], 0, 0, 0);
    __builtin_amdgcn_s_setprio(0);
    asm volatile("s_waitcnt vmcnt(6)" ::: "memory");   // (kt+1,kh0) DMA landed
    __builtin_amdgcn_s_barrier();                      // publish across waves

    // ---- phase B1: prefetch bfr0,af03(next tile kh0); MFMA acc[4-7] (af47 x bfr1) ----
    #pragma unroll
    for (int ni = 0; ni < 4; ++ni) bfr0[ni] = LDBp(BbN, ni, 0);
    #pragma unroll
    for (int j = 0; j < 4; ++j) af03[j] = LDAp(AbN, j, 0);
    stB(kt + 2, 0);
    asm volatile("s_waitcnt lgkmcnt(8)" ::: "memory");
    __builtin_amdgcn_sched_barrier(0);
    __builtin_amdgcn_s_setprio(1);
    #pragma unroll
    for (int j = 0; j < 4; ++j)
      #pragma unroll
      for (int ni = 0; ni < 4; ++ni)
        acc[4 + j][ni] = __builtin_amdgcn_mfma_f32_16x16x32_bf16(af47[j], bfr1[ni], acc[4 + j][ni], 0, 0, 0);
    __builtin_amdgcn_s_setprio(0);
    __builtin_amdgcn_s_barrier();
  }
#undef LDAp
#undef LDBp

  // Epilogue: y = lrelu(acc*fac + noise*nscale + bias) * sqrt(2)
  const float ns = nscale_p[0];
  float nz[4];
  #pragma unroll
  for (int ni = 0; ni < 4; ++ni) {
    int pix = pimg + wn * 64 + ni * 16 + l15;
    nz[ni] = noise[b * PIX + pix] * ns;
  }
  #pragma unroll
  for (int mi = 0; mi < 8; ++mi) {
    int o = mt * 256 + wm * 128 + mi * 16 + l4 * 4;
    f32x4 fv = *(const f32x4*)&fac[b * COUT + o];
    f32x4 bv = *(const f32x4*)&bias[o];
    #pragma unroll
    for (int r = 0; r < 4; ++r) {
      float* yp = y + (size_t)(b * COUT + o + r) * PIX + pimg + wn * 64 + l15;
      #pragma unroll
      for (int ni = 0; ni < 4; ++ni) {
        float v = acc[mi][ni][r] * fv[r] + nz[ni] + bv[r];
        v = (v > 0.0f ? v : 0.2f * v) * kGain;
        yp[ni * 16] = v;
      }
    }
  }
}

// ---------------------------------------------------------------------------
extern "C" void kernel_launch(void* const* d_in, const int* in_sizes, int n_in,
                              void* d_out, int out_size, void* d_ws, size_t ws_size,
                              hipStream_t stream) {
  const float* x      = (const float*)d_in[0];
  const float* w      = (const float*)d_in[1];
  const float* noise  = (const float*)d_in[2];
  const float* aff_w  = (const float*)d_in[3];
  const float* aff_b  = (const float*)d_in[4];
  const float* conv_w = (const float*)d_in[5];
  const float* nscale = (const float*)d_in[6];
  const float* bias   = (const float*)d_in[7];
  float* y = (float*)d_out;

  char* ws = (char*)d_ws;
  float* style = (float*)(ws);                          // 16 KB
  float* fac   = (float*)(ws + 16384);                  // 16 KB
  float* cw2   = (float*)(ws + 32768);                  // 1 MB
  float* zbuf  = (float*)(ws + 1081344);                // 256 B zeros
  u16*   wbt   = (u16*)(ws + 1081600);                  // 4.5 MB panels
  u16*   xst   = (u16*)(ws + 5800192);                  // 32 MB panels

  style_k<<<16, 256, 0, stream>>>(w, aff_w, aff_b, style, zbuf);
  cw2_k<<<1024, 256, 0, stream>>>(conv_w, cw2);
  fac_k<<<1024, 256, 0, stream>>>(style, cw2, fac);
  wcast_k<<<1024, 256, 0, stream>>>(conv_w, wbt);
  modx_k<<<dim3(64, 8, 8), 256, 0, stream>>>(x, style, xst);
  gemm_k<<<256, 512, 0, stream>>>(wbt, xst, fac, noise, nscale, bias, zbuf, y);
}

// Round 6
// 204.259 us; speedup vs baseline: 1.1338x; 1.0628x over previous
//
#include <hip/hip_runtime.h>
#include <hip/hip_bf16.h>

typedef unsigned short u16;

#define BATCH 8
#define CIN 512
#define COUT 512
#define SDIM 512
#define RES 64
#define PIX (RES * RES)          // 4096
#define NKT 72                   // K-tiles of 64: 9 taps * 8 cin-blocks
#define PPIX 4356                // padded 66x66
#define PANEL_E 139392           // PPIX*32 elems per padded B panel

__device__ __constant__ static const float kAffScale  = 0.04419417382415922f;   // 1/sqrt(512)
__device__ __constant__ static const float kConvScale = 0.014731391274719742f;  // 1/sqrt(512*9)
__device__ __constant__ static const float kGain      = 1.4142135623730951f;    // sqrt(2)

typedef __bf16 bf16x8 __attribute__((ext_vector_type(8)));
typedef float  f32x4  __attribute__((ext_vector_type(4)));

// ---------------------------------------------------------------------------
// Kernel 1: style[b][c] = (w[b] . affine_w[c]) * AFF_SCALE + affine_b[c]
// ---------------------------------------------------------------------------
__global__ void style_k(const float* __restrict__ w, const float* __restrict__ aw,
                        const float* __restrict__ ab, float* __restrict__ style) {
  int tid = blockIdx.x * 256 + threadIdx.x;      // 0..4095
  int b = tid >> 9, c = tid & 511;
  const float* wp = w + b * SDIM;
  const float* ap = aw + c * SDIM;
  float s = 0.0f;
  for (int k = 0; k < SDIM; ++k) s += wp[k] * ap[k];
  style[tid] = s * kAffScale + ab[c];
}

// ---------------------------------------------------------------------------
// Kernel 2: cw2[o][i] = sum_t conv_w[o][i][t]^2
// ---------------------------------------------------------------------------
__global__ void cw2_k(const float* __restrict__ cw, float* __restrict__ cw2) {
  int tid = blockIdx.x * 256 + threadIdx.x;      // o*512+i
  const float* p = cw + tid * 9;
  float s = 0.0f;
  #pragma unroll
  for (int t = 0; t < 9; ++t) { float v = p[t]; s += v * v; }
  cw2[tid] = s;
}

// ---------------------------------------------------------------------------
// Kernel 3: fac[b][o] = CONV_SCALE * rsqrt(CONV_SCALE^2 * sum_i style^2*cw2 + 1e-8)
// ---------------------------------------------------------------------------
__global__ void fac_k(const float* __restrict__ style, const float* __restrict__ cw2,
                      float* __restrict__ fac) {
  int wid  = blockIdx.x * 4 + (threadIdx.x >> 6); // 0..4095
  int lane = threadIdx.x & 63;
  int b = wid >> 9, o = wid & 511;
  const float* st = style + b * CIN;
  const float* c2 = cw2 + o * CIN;
  float s = 0.0f;
  for (int i = lane; i < CIN; i += 64) { float sv = st[i]; s += sv * sv * c2[i]; }
  #pragma unroll
  for (int off = 32; off; off >>= 1) s += __shfl_xor(s, off);
  if (lane == 0) {
    float d = rsqrtf(s * kConvScale * kConvScale + 1e-8f);
    fac[wid] = d * kConvScale;
  }
}

// ---------------------------------------------------------------------------
// Kernel 4: wbt[(tap*16+sl)][o][j] = bf16(conv_w[o][sl*32+j][tap])
// ---------------------------------------------------------------------------
__global__ void wcast_k(const float* __restrict__ cw, u16* __restrict__ wbt) {
  int tid = blockIdx.x * 256 + threadIdx.x;      // o*512 + i
  int o = tid >> 9, i = tid & 511;
  const float* p = cw + tid * 9;
  #pragma unroll
  for (int t = 0; t < 9; ++t) {
    __hip_bfloat16 h = __float2bfloat16(p[t]);
    wbt[((size_t)(t * 16 + (i >> 5)) * 512 + o) * 32 + (i & 31)] = *(u16*)&h;
  }
}

// ---------------------------------------------------------------------------
// Kernel 5a: zero the 1-pixel borders of all 128 padded B panels
// ---------------------------------------------------------------------------
__global__ void bz_k(u16* __restrict__ xst) {
  int idx = blockIdx.x * 256 + threadIdx.x;      // panel*4356 + pix
  if (idx >= 128 * PPIX) return;
  int pan = idx / PPIX, pix = idx - pan * PPIX;
  int h = pix / 66, w = pix - h * 66;
  if (h == 0 || h == 65 || w == 0 || w == 65) {
    u16* p = xst + (size_t)pan * PANEL_E + (size_t)pix * 32;
    int4 z = make_int4(0, 0, 0, 0);
    ((int4*)p)[0] = z; ((int4*)p)[1] = z; ((int4*)p)[2] = z; ((int4*)p)[3] = z;
  }
}

// ---------------------------------------------------------------------------
// Kernel 5b: xst[(b*16+sl)][(h+1)*66+(w+1)][j] = bf16(x[b][sl*32+j][h*64+w]*style)
// ---------------------------------------------------------------------------
__global__ void modx_k(const float* __restrict__ x, const float* __restrict__ style,
                       u16* __restrict__ xst) {
  __shared__ float t[64][65];
  int b  = blockIdx.z;
  int it = blockIdx.y * 64;                      // cin tile base
  int pt = blockIdx.x * 64;                      // pixel tile base
  int tp = threadIdx.x & 63;
  int tr = threadIdx.x >> 6;                     // 0..3
  for (int r = tr; r < 64; r += 4) {
    int i = it + r;
    t[r][tp] = x[(b * CIN + i) * PIX + pt + tp] * style[b * CIN + i];
  }
  __syncthreads();
  int i = it + tp;
  size_t pbase = (size_t)(b * 16 + (i >> 5)) * PANEL_E + (i & 31);
  for (int r = tr; r < 64; r += 4) {
    int pix = pt + r, h = pix >> 6, w = pix & 63;
    __hip_bfloat16 hh = __float2bfloat16(t[tp][r]);
    xst[pbase + (size_t)((h + 1) * 66 + (w + 1)) * 32] = *(u16*)&hh;
  }
}

// ---------------------------------------------------------------------------
// Kernel 6: implicit-GEMM conv, r3 8-phase schedule verbatim; VALU diet:
// padded B panels (no halo predicates), linear A panel index (2*ktx+kh),
// kt-loop unrolled x2 so dbuf index is a literal (imm-folded ds_read addrs).
// BM=BN=256, BK=64 (2 kh-slices), 8 waves (2Mx4N), wave out 128x64.
// ---------------------------------------------------------------------------
__launch_bounds__(512, 2)
__global__ void gemm_k(const u16* __restrict__ wbt, const u16* __restrict__ xst,
                       const float* __restrict__ fac, const float* __restrict__ noise,
                       const float* __restrict__ nscale_p, const float* __restrict__ bias,
                       float* __restrict__ y) {
  __shared__ __align__(16) u16 Abuf[2][16384];   // [dbuf][kh*8192 + row*32 + slot*8]
  __shared__ __align__(16) u16 Bbuf[2][16384];

  const int tid = threadIdx.x;
  const int bid = blockIdx.x;                    // 0..255
  const int swz = (bid & 7) * 32 + (bid >> 3);   // XCD-chunked (256 % 8 == 0)
  const int mt = swz >> 7;                       // 0..1   cout tile
  const int nt = swz & 127;                      // 0..127 pixel tile
  const int b  = nt >> 4;                        // image
  const int pimg  = (nt & 15) * 256;             // pixel base within image
  const int hbase = pimg >> 6;                   // image row base

  const int lane = tid & 63;
  const int wv = tid >> 6;                       // 0..7
  const int wm = wv >> 2;                        // 0..1  (128 out-rows)
  const int wn = wv & 3;                         // 0..3  (64 out-cols)
  const int l15 = lane & 15, l4 = lane >> 4;
  const int slot = (l4 ^ ((l15 >> 1) & 3)) * 8;  // swizzled 16B slot (u16 units)

  // ---- staging per-thread constants: chunk c = p*512+tid, row=c>>2, slot=c&3
  const int sgE = ((tid & 3) ^ ((tid >> 3) & 3)) << 3;  // swizzled source elem offset
  int aoffE[2], ppB[2];
  #pragma unroll
  for (int p = 0; p < 2; ++p) {
    int row = (p * 512 + tid) >> 2;              // 0..255
    aoffE[p] = (mt * 256 + row) * 32 + sgE;      // elems within A panel [512][32]
    ppB[p]   = ((hbase + (row >> 6) + 1) * 66 + (row & 63) + 1) * 32 + sgE; // padded
  }

  auto stA = [&](int ktx, int kh) {
    if (ktx >= NKT) ktx -= NKT;
    const int d = ktx & 1;
    const u16* pan = wbt + ((size_t)(2 * ktx + kh) << 14);  // linear panel index
    #pragma unroll
    for (int p = 0; p < 2; ++p) {
      __builtin_amdgcn_global_load_lds(
          (const __attribute__((address_space(1))) void*)(pan + aoffE[p]),
          (__attribute__((address_space(3))) void*)(&Abuf[d][kh * 8192 + (p * 512 + tid) * 8]),
          16, 0, 0);
    }
  };
  auto stB = [&](int ktx, int kh) {
    if (ktx >= NKT) ktx -= NKT;
    const int tap = ktx >> 3;                    // uniform
    const int t3  = (tap >= 6) ? 2 : (tap >= 3 ? 1 : 0);
    const int shiftE = ((t3 - 1) * 66 + (tap - t3 * 3 - 1)) * 32;  // (dy*66+dx)*32
    const int d = ktx & 1;
    const u16* pan = xst + (size_t)(b * 16 + ((ktx & 7) << 1) + kh) * PANEL_E + shiftE;
    #pragma unroll
    for (int p = 0; p < 2; ++p) {
      __builtin_amdgcn_global_load_lds(
          (const __attribute__((address_space(1))) void*)(pan + ppB[p]),
          (__attribute__((address_space(3))) void*)(&Bbuf[d][kh * 8192 + (p * 512 + tid) * 8]),
          16, 0, 0);
    }
  };

  f32x4 acc[8][4];
  #pragma unroll
  for (int i = 0; i < 8; ++i)
    #pragma unroll
    for (int j = 0; j < 4; ++j) acc[i][j] = (f32x4){0.f, 0.f, 0.f, 0.f};

  // Prologue: 6 DMA quanta (12 loads); kt0 kh0 valid after vmcnt(8)+barrier.
  stA(0, 0); stB(0, 0); stA(0, 1); stB(0, 1); stA(1, 0); stB(1, 0);
  asm volatile("s_waitcnt vmcnt(8)" ::: "memory");
  __builtin_amdgcn_s_barrier();

#define LDA(D, mi, kh) (*(const bf16x8*)&Abuf[D][(kh) * 8192 + (wm * 128 + (mi) * 16 + l15) * 32 + slot])
#define LDB(D, ni, kh) (*(const bf16x8*)&Bbuf[D][(kh) * 8192 + (wn * 64 + (ni) * 16 + l15) * 32 + slot])

#define TILE(D, KT) {                                                          \
    bf16x8 bfr[4], af[4];                                                      \
    /* phase 0: kh0 mi0-3 */                                                   \
    _Pragma("unroll") for (int ni = 0; ni < 4; ++ni) bfr[ni] = LDB(D, ni, 0);  \
    _Pragma("unroll") for (int j = 0; j < 4; ++j) af[j] = LDA(D, j, 0);        \
    stA((KT) + 1, 1);                                                          \
    __builtin_amdgcn_s_barrier();                                              \
    asm volatile("s_waitcnt lgkmcnt(0)" ::: "memory");                         \
    __builtin_amdgcn_sched_barrier(0);                                         \
    __builtin_amdgcn_s_setprio(1);                                             \
    _Pragma("unroll") for (int j = 0; j < 4; ++j)                              \
      _Pragma("unroll") for (int ni = 0; ni < 4; ++ni)                         \
        acc[j][ni] = __builtin_amdgcn_mfma_f32_16x16x32_bf16(af[j], bfr[ni], acc[j][ni], 0, 0, 0); \
    __builtin_amdgcn_s_setprio(0);                                             \
    __builtin_amdgcn_s_barrier();                                              \
    /* phase 1: kh0 mi4-7 */                                                   \
    _Pragma("unroll") for (int j = 0; j < 4; ++j) af[j] = LDA(D, 4 + j, 0);    \
    stB((KT) + 1, 1);                                                          \
    __builtin_amdgcn_s_barrier();                                              \
    asm volatile("s_waitcnt lgkmcnt(0)" ::: "memory");                         \
    __builtin_amdgcn_sched_barrier(0);                                         \
    __builtin_amdgcn_s_setprio(1);                                             \
    _Pragma("unroll") for (int j = 0; j < 4; ++j)                              \
      _Pragma("unroll") for (int ni = 0; ni < 4; ++ni)                         \
        acc[4 + j][ni] = __builtin_amdgcn_mfma_f32_16x16x32_bf16(af[j], bfr[ni], acc[4 + j][ni], 0, 0, 0); \
    __builtin_amdgcn_s_setprio(0);                                             \
    asm volatile("s_waitcnt vmcnt(8)" ::: "memory");                           \
    __builtin_amdgcn_s_barrier();                                              \
    /* phase 2: kh1 mi0-3 */                                                   \
    _Pragma("unroll") for (int ni = 0; ni < 4; ++ni) bfr[ni] = LDB(D, ni, 1);  \
    _Pragma("unroll") for (int j = 0; j < 4; ++j) af[j] = LDA(D, j, 1);        \
    stA((KT) + 2, 0);                                                          \
    __builtin_amdgcn_s_barrier();                                              \
    asm volatile("s_waitcnt lgkmcnt(0)" ::: "memory");                         \
    __builtin_amdgcn_sched_barrier(0);                                         \
    __builtin_amdgcn_s_setprio(1);                                             \
    _Pragma("unroll") for (int j = 0; j < 4; ++j)                              \
      _Pragma("unroll") for (int ni = 0; ni < 4; ++ni)                         \
        acc[j][ni] = __builtin_amdgcn_mfma_f32_16x16x32_bf16(af[j], bfr[ni], acc[j][ni], 0, 0, 0); \
    __builtin_amdgcn_s_setprio(0);                                             \
    __builtin_amdgcn_s_barrier();                                              \
    /* phase 3: kh1 mi4-7 */                                                   \
    _Pragma("unroll") for (int j = 0; j < 4; ++j) af[j] = LDA(D, 4 + j, 1);    \
    stB((KT) + 2, 0);                                                          \
    __builtin_amdgcn_s_barrier();                                              \
    asm volatile("s_waitcnt lgkmcnt(0)" ::: "memory");                         \
    __builtin_amdgcn_sched_barrier(0);                                         \
    __builtin_amdgcn_s_setprio(1);                                             \
    _Pragma("unroll") for (int j = 0; j < 4; ++j)                              \
      _Pragma("unroll") for (int ni = 0; ni < 4; ++ni)                         \
        acc[4 + j][ni] = __builtin_amdgcn_mfma_f32_16x16x32_bf16(af[j], bfr[ni], acc[4 + j][ni], 0, 0, 0); \
    __builtin_amdgcn_s_setprio(0);                                             \
    asm volatile("s_waitcnt vmcnt(8)" ::: "memory");                           \
    __builtin_amdgcn_s_barrier();                                              \
  }

  for (int kt = 0; kt < NKT; kt += 2) {
    TILE(0, kt)
    TILE(1, kt + 1)
  }
#undef TILE
#undef LDA
#undef LDB

  // Epilogue: y = lrelu(acc*fac + noise*nscale + bias) * sqrt(2)
  const float ns = nscale_p[0];
  float nz[4];
  #pragma unroll
  for (int ni = 0; ni < 4; ++ni) {
    int pix = pimg + wn * 64 + ni * 16 + l15;
    nz[ni] = noise[b * PIX + pix] * ns;
  }
  #pragma unroll
  for (int mi = 0; mi < 8; ++mi) {
    int o = mt * 256 + wm * 128 + mi * 16 + l4 * 4;
    f32x4 fv = *(const f32x4*)&fac[b * COUT + o];
    f32x4 bv = *(const f32x4*)&bias[o];
    #pragma unroll
    for (int r = 0; r < 4; ++r) {
      float* yp = y + (size_t)(b * COUT + o + r) * PIX + pimg + wn * 64 + l15;
      #pragma unroll
      for (int ni = 0; ni < 4; ++ni) {
        float v = acc[mi][ni][r] * fv[r] + nz[ni] + bv[r];
        v = (v > 0.0f ? v : 0.2f * v) * kGain;
        yp[ni * 16] = v;
      }
    }
  }
}

// ---------------------------------------------------------------------------
extern "C" void kernel_launch(void* const* d_in, const int* in_sizes, int n_in,
                              void* d_out, int out_size, void* d_ws, size_t ws_size,
                              hipStream_t stream) {
  const float* x      = (const float*)d_in[0];
  const float* w      = (const float*)d_in[1];
  const float* noise  = (const float*)d_in[2];
  const float* aff_w  = (const float*)d_in[3];
  const float* aff_b  = (const float*)d_in[4];
  const float* conv_w = (const float*)d_in[5];
  const float* nscale = (const float*)d_in[6];
  const float* bias   = (const float*)d_in[7];
  float* y = (float*)d_out;

  char* ws = (char*)d_ws;
  float* style = (float*)(ws);                          // 16 KB
  float* fac   = (float*)(ws + 16384);                  // 16 KB
  float* cw2   = (float*)(ws + 32768);                  // 1 MB
  u16*   wbt   = (u16*)(ws + 1081600);                  // 4.5 MB panels
  u16*   xst   = (u16*)(ws + 5800192);                  // 128 padded panels, 35.7 MB

  style_k<<<16, 256, 0, stream>>>(w, aff_w, aff_b, style);
  cw2_k<<<1024, 256, 0, stream>>>(conv_w, cw2);
  fac_k<<<1024, 256, 0, stream>>>(style, cw2, fac);
  wcast_k<<<1024, 256, 0, stream>>>(conv_w, wbt);
  bz_k<<<(128 * PPIX + 255) / 256, 256, 0, stream>>>(xst);
  modx_k<<<dim3(64, 8, 8), 256, 0, stream>>>(x, style, xst);
  gemm_k<<<256, 512, 0, stream>>>(wbt, xst, fac, noise, nscale, bias, y);
}

// Round 7
// 198.833 us; speedup vs baseline: 1.1647x; 1.0273x over previous
//
#include <hip/hip_runtime.h>
#include <hip/hip_bf16.h>

typedef unsigned short u16;

#define BATCH 8
#define CIN 512
#define COUT 512
#define SDIM 512
#define RES 64
#define PIX (RES * RES)          // 4096
#define NKT 72                   // K-tiles of 64: 9 taps * 8 cin-blocks
#define PPIX 4356                // padded 66x66
#define PANEL_E 139392           // PPIX*32 elems per padded B panel

__device__ __constant__ static const float kAffScale  = 0.04419417382415922f;   // 1/sqrt(512)
__device__ __constant__ static const float kConvScale = 0.014731391274719742f;  // 1/sqrt(512*9)
__device__ __constant__ static const float kGain      = 1.4142135623730951f;    // sqrt(2)

typedef __bf16 bf16x8 __attribute__((ext_vector_type(8)));
typedef float  f32x4  __attribute__((ext_vector_type(4)));

// ---------------------------------------------------------------------------
// Kernel 1: style[b][c] = (w[b] . affine_w[c]) * AFF_SCALE + affine_b[c]
// ---------------------------------------------------------------------------
__global__ void style_k(const float* __restrict__ w, const float* __restrict__ aw,
                        const float* __restrict__ ab, float* __restrict__ style) {
  int tid = blockIdx.x * 256 + threadIdx.x;      // 0..4095
  int b = tid >> 9, c = tid & 511;
  const float* wp = w + b * SDIM;
  const float* ap = aw + c * SDIM;
  float s = 0.0f;
  for (int k = 0; k < SDIM; ++k) s += wp[k] * ap[k];
  style[tid] = s * kAffScale + ab[c];
}

// ---------------------------------------------------------------------------
// Kernel 2: cw2[o][i] = sum_t conv_w[o][i][t]^2
// ---------------------------------------------------------------------------
__global__ void cw2_k(const float* __restrict__ cw, float* __restrict__ cw2) {
  int tid = blockIdx.x * 256 + threadIdx.x;      // o*512+i
  const float* p = cw + tid * 9;
  float s = 0.0f;
  #pragma unroll
  for (int t = 0; t < 9; ++t) { float v = p[t]; s += v * v; }
  cw2[tid] = s;
}

// ---------------------------------------------------------------------------
// Kernel 3: fac[b][o] = CONV_SCALE * rsqrt(CONV_SCALE^2 * sum_i style^2*cw2 + 1e-8)
// ---------------------------------------------------------------------------
__global__ void fac_k(const float* __restrict__ style, const float* __restrict__ cw2,
                      float* __restrict__ fac) {
  int wid  = blockIdx.x * 4 + (threadIdx.x >> 6); // 0..4095
  int lane = threadIdx.x & 63;
  int b = wid >> 9, o = wid & 511;
  const float* st = style + b * CIN;
  const float* c2 = cw2 + o * CIN;
  float s = 0.0f;
  for (int i = lane; i < CIN; i += 64) { float sv = st[i]; s += sv * sv * c2[i]; }
  #pragma unroll
  for (int off = 32; off; off >>= 1) s += __shfl_xor(s, off);
  if (lane == 0) {
    float d = rsqrtf(s * kConvScale * kConvScale + 1e-8f);
    fac[wid] = d * kConvScale;
  }
}

// ---------------------------------------------------------------------------
// Kernel 4: wbt[(tap*16+sl)][o][j] = bf16(conv_w[o][sl*32+j][tap])
// ---------------------------------------------------------------------------
__global__ void wcast_k(const float* __restrict__ cw, u16* __restrict__ wbt) {
  int tid = blockIdx.x * 256 + threadIdx.x;      // o*512 + i
  int o = tid >> 9, i = tid & 511;
  const float* p = cw + tid * 9;
  #pragma unroll
  for (int t = 0; t < 9; ++t) {
    __hip_bfloat16 h = __float2bfloat16(p[t]);
    wbt[((size_t)(t * 16 + (i >> 5)) * 512 + o) * 32 + (i & 31)] = *(u16*)&h;
  }
}

// ---------------------------------------------------------------------------
// Kernel 5a: zero the 1-pixel borders of all 128 padded B panels
// ---------------------------------------------------------------------------
__global__ void bz_k(u16* __restrict__ xst) {
  int idx = blockIdx.x * 256 + threadIdx.x;      // panel*4356 + pix
  if (idx >= 128 * PPIX) return;
  int pan = idx / PPIX, pix = idx - pan * PPIX;
  int h = pix / 66, w = pix - h * 66;
  if (h == 0 || h == 65 || w == 0 || w == 65) {
    u16* p = xst + (size_t)pan * PANEL_E + (size_t)pix * 32;
    int4 z = make_int4(0, 0, 0, 0);
    ((int4*)p)[0] = z; ((int4*)p)[1] = z; ((int4*)p)[2] = z; ((int4*)p)[3] = z;
  }
}

// ---------------------------------------------------------------------------
// Kernel 5b: xst[(b*16+sl)][(h+1)*66+(w+1)][j] = bf16(x[b][sl*32+j][h*64+w]*style)
// ---------------------------------------------------------------------------
__global__ void modx_k(const float* __restrict__ x, const float* __restrict__ style,
                       u16* __restrict__ xst) {
  __shared__ float t[64][65];
  int b  = blockIdx.z;
  int it = blockIdx.y * 64;                      // cin tile base
  int pt = blockIdx.x * 64;                      // pixel tile base
  int tp = threadIdx.x & 63;
  int tr = threadIdx.x >> 6;                     // 0..3
  for (int r = tr; r < 64; r += 4) {
    int i = it + r;
    t[r][tp] = x[(b * CIN + i) * PIX + pt + tp] * style[b * CIN + i];
  }
  __syncthreads();
  int i = it + tp;
  size_t pbase = (size_t)(b * 16 + (i >> 5)) * PANEL_E + (i & 31);
  for (int r = tr; r < 64; r += 4) {
    int pix = pt + r, h = pix >> 6, w = pix & 63;
    __hip_bfloat16 hh = __float2bfloat16(t[tp][r]);
    xst[pbase + (size_t)((h + 1) * 66 + (w + 1)) * 32] = *(u16*)&hh;
  }
}

// ---------------------------------------------------------------------------
// Kernel 6: implicit-GEMM conv. Per kh-half: read-heavy phase (12 ds_reads:
// bfr+af+afp prefetch, issue-order pinned) -> barrier -> lgkmcnt(4) ->
// 16 MFMA -> barrier -> read-free phase (stage only) -> lgkmcnt(0) (drains
// the 4 prefetched) -> 16 MFMA -> vmcnt(8) -> barrier. 6 barriers/K-tile,
// all waits counted; vmcnt never 0 in the main loop.
// BM=BN=256, BK=64 (2 kh-slices), 8 waves (2Mx4N), wave out 128x64.
// ---------------------------------------------------------------------------
__launch_bounds__(512, 2)
__global__ void gemm_k(const u16* __restrict__ wbt, const u16* __restrict__ xst,
                       const float* __restrict__ fac, const float* __restrict__ noise,
                       const float* __restrict__ nscale_p, const float* __restrict__ bias,
                       float* __restrict__ y) {
  __shared__ __align__(16) u16 Abuf[2][16384];   // [dbuf][kh*8192 + row*32 + slot*8]
  __shared__ __align__(16) u16 Bbuf[2][16384];

  const int tid = threadIdx.x;
  const int bid = blockIdx.x;                    // 0..255
  const int swz = (bid & 7) * 32 + (bid >> 3);   // XCD-chunked (256 % 8 == 0)
  const int mt = swz >> 7;                       // 0..1   cout tile
  const int nt = swz & 127;                      // 0..127 pixel tile
  const int b  = nt >> 4;                        // image
  const int pimg  = (nt & 15) * 256;             // pixel base within image
  const int hbase = pimg >> 6;                   // image row base

  const int lane = tid & 63;
  const int wv = tid >> 6;                       // 0..7
  const int wm = wv >> 2;                        // 0..1  (128 out-rows)
  const int wn = wv & 3;                         // 0..3  (64 out-cols)
  const int l15 = lane & 15, l4 = lane >> 4;
  const int slot = (l4 ^ ((l15 >> 1) & 3)) * 8;  // swizzled 16B slot (u16 units)

  // ---- staging per-thread constants: chunk c = p*512+tid, row=c>>2, slot=c&3
  const int sgE = ((tid & 3) ^ ((tid >> 3) & 3)) << 3;  // swizzled source elem offset
  int aoffE[2], ppB[2];
  #pragma unroll
  for (int p = 0; p < 2; ++p) {
    int row = (p * 512 + tid) >> 2;              // 0..255
    aoffE[p] = (mt * 256 + row) * 32 + sgE;      // elems within A panel [512][32]
    ppB[p]   = ((hbase + (row >> 6) + 1) * 66 + (row & 63) + 1) * 32 + sgE; // padded
  }

  auto stA = [&](int ktx, int kh) {
    if (ktx >= NKT) ktx -= NKT;
    const int d = ktx & 1;
    const u16* pan = wbt + ((size_t)(2 * ktx + kh) << 14);  // linear panel index
    #pragma unroll
    for (int p = 0; p < 2; ++p) {
      __builtin_amdgcn_global_load_lds(
          (const __attribute__((address_space(1))) void*)(pan + aoffE[p]),
          (__attribute__((address_space(3))) void*)(&Abuf[d][kh * 8192 + (p * 512 + tid) * 8]),
          16, 0, 0);
    }
  };
  auto stB = [&](int ktx, int kh) {
    if (ktx >= NKT) ktx -= NKT;
    const int tap = ktx >> 3;                    // uniform
    const int t3  = (tap >= 6) ? 2 : (tap >= 3 ? 1 : 0);
    const int shiftE = ((t3 - 1) * 66 + (tap - t3 * 3 - 1)) * 32;  // (dy*66+dx)*32
    const int d = ktx & 1;
    const u16* pan = xst + (size_t)(b * 16 + ((ktx & 7) << 1) + kh) * PANEL_E + shiftE;
    #pragma unroll
    for (int p = 0; p < 2; ++p) {
      __builtin_amdgcn_global_load_lds(
          (const __attribute__((address_space(1))) void*)(pan + ppB[p]),
          (__attribute__((address_space(3))) void*)(&Bbuf[d][kh * 8192 + (p * 512 + tid) * 8]),
          16, 0, 0);
    }
  };

  f32x4 acc[8][4];
  #pragma unroll
  for (int i = 0; i < 8; ++i)
    #pragma unroll
    for (int j = 0; j < 4; ++j) acc[i][j] = (f32x4){0.f, 0.f, 0.f, 0.f};

  // Prologue: 6 DMA quanta (12 loads); kt0 kh0 valid after vmcnt(8)+barrier.
  stA(0, 0); stB(0, 0); stA(0, 1); stB(0, 1); stA(1, 0); stB(1, 0);
  asm volatile("s_waitcnt vmcnt(8)" ::: "memory");
  __builtin_amdgcn_s_barrier();

#define LDA(D, mi, kh) (*(const bf16x8*)&Abuf[D][(kh) * 8192 + (wm * 128 + (mi) * 16 + l15) * 32 + slot])
#define LDB(D, ni, kh) (*(const bf16x8*)&Bbuf[D][(kh) * 8192 + (wn * 64 + (ni) * 16 + l15) * 32 + slot])

  // One kh-half: reads(8) | pin | prefetch(4) | stage-A | bar | lgkm(4) |
  // MFMA lo | bar | stage-B | lgkm(0) | MFMA hi | vmcnt(8) | bar
#define HALF(D, KT, KH, STKT, STKH) {                                          \
    bf16x8 bfr[4], af[4], afp[4];                                              \
    _Pragma("unroll") for (int ni = 0; ni < 4; ++ni) bfr[ni] = LDB(D, ni, KH); \
    _Pragma("unroll") for (int j = 0; j < 4; ++j) af[j] = LDA(D, j, KH);       \
    __builtin_amdgcn_sched_barrier(0);  /* pin: these 8 are the oldest lgkm */ \
    _Pragma("unroll") for (int j = 0; j < 4; ++j) afp[j] = LDA(D, 4 + j, KH);  \
    stA(STKT, STKH);                                                           \
    __builtin_amdgcn_s_barrier();                                              \
    asm volatile("s_waitcnt lgkmcnt(4)" ::: "memory");                         \
    __builtin_amdgcn_sched_barrier(0);                                         \
    __builtin_amdgcn_s_setprio(1);                                             \
    _Pragma("unroll") for (int j = 0; j < 4; ++j)                              \
      _Pragma("unroll") for (int ni = 0; ni < 4; ++ni)                         \
        acc[j][ni] = __builtin_amdgcn_mfma_f32_16x16x32_bf16(af[j], bfr[ni], acc[j][ni], 0, 0, 0); \
    __builtin_amdgcn_s_setprio(0);                                             \
    __builtin_amdgcn_s_barrier();                                              \
    stB(STKT, STKH);                                                           \
    asm volatile("s_waitcnt lgkmcnt(0)" ::: "memory");                         \
    __builtin_amdgcn_sched_barrier(0);                                         \
    __builtin_amdgcn_s_setprio(1);                                             \
    _Pragma("unroll") for (int j = 0; j < 4; ++j)                              \
      _Pragma("unroll") for (int ni = 0; ni < 4; ++ni)                         \
        acc[4 + j][ni] = __builtin_amdgcn_mfma_f32_16x16x32_bf16(afp[j], bfr[ni], acc[4 + j][ni], 0, 0, 0); \
    __builtin_amdgcn_s_setprio(0);                                             \
    asm volatile("s_waitcnt vmcnt(8)" ::: "memory");                           \
    __builtin_amdgcn_s_barrier();                                              \
  }

  for (int kt = 0; kt < NKT; kt += 2) {
    HALF(0, kt, 0, kt + 1, 1)       // kh0; stages (kt+1, kh1)
    HALF(0, kt, 1, kt + 2, 0)       // kh1; stages (kt+2, kh0)
    HALF(1, kt + 1, 0, kt + 2, 1)   // next tile kh0; stages (kt+2, kh1)
    HALF(1, kt + 1, 1, kt + 3, 0)   // next tile kh1; stages (kt+3, kh0)
  }
#undef HALF
#undef LDA
#undef LDB

  // Epilogue: y = lrelu(acc*fac + noise*nscale + bias) * sqrt(2)
  const float ns = nscale_p[0];
  float nz[4];
  #pragma unroll
  for (int ni = 0; ni < 4; ++ni) {
    int pix = pimg + wn * 64 + ni * 16 + l15;
    nz[ni] = noise[b * PIX + pix] * ns;
  }
  #pragma unroll
  for (int mi = 0; mi < 8; ++mi) {
    int o = mt * 256 + wm * 128 + mi * 16 + l4 * 4;
    f32x4 fv = *(const f32x4*)&fac[b * COUT + o];
    f32x4 bv = *(const f32x4*)&bias[o];
    #pragma unroll
    for (int r = 0; r < 4; ++r) {
      float* yp = y + (size_t)(b * COUT + o + r) * PIX + pimg + wn * 64 + l15;
      #pragma unroll
      for (int ni = 0; ni < 4; ++ni) {
        float v = acc[mi][ni][r] * fv[r] + nz[ni] + bv[r];
        v = (v > 0.0f ? v : 0.2f * v) * kGain;
        yp[ni * 16] = v;
      }
    }
  }
}

// ---------------------------------------------------------------------------
extern "C" void kernel_launch(void* const* d_in, const int* in_sizes, int n_in,
                              void* d_out, int out_size, void* d_ws, size_t ws_size,
                              hipStream_t stream) {
  const float* x      = (const float*)d_in[0];
  const float* w      = (const float*)d_in[1];
  const float* noise  = (const float*)d_in[2];
  const float* aff_w  = (const float*)d_in[3];
  const float* aff_b  = (const float*)d_in[4];
  const float* conv_w = (const float*)d_in[5];
  const float* nscale = (const float*)d_in[6];
  const float* bias   = (const float*)d_in[7];
  float* y = (float*)d_out;

  char* ws = (char*)d_ws;
  float* style = (float*)(ws);                          // 16 KB
  float* fac   = (float*)(ws + 16384);                  // 16 KB
  float* cw2   = (float*)(ws + 32768);                  // 1 MB
  u16*   wbt   = (u16*)(ws + 1081600);                  // 4.5 MB panels
  u16*   xst   = (u16*)(ws + 5800192);                  // 128 padded panels, 35.7 MB

  style_k<<<16, 256, 0, stream>>>(w, aff_w, aff_b, style);
  cw2_k<<<1024, 256, 0, stream>>>(conv_w, cw2);
  fac_k<<<1024, 256, 0, stream>>>(style, cw2, fac);
  wcast_k<<<1024, 256, 0, stream>>>(conv_w, wbt);
  bz_k<<<(128 * PPIX + 255) / 256, 256, 0, stream>>>(xst);
  modx_k<<<dim3(64, 8, 8), 256, 0, stream>>>(x, style, xst);
  gemm_k<<<256, 512, 0, stream>>>(wbt, xst, fac, noise, nscale, bias, y);
}

// Round 8
// 191.479 us; speedup vs baseline: 1.2094x; 1.0384x over previous
//
#include <hip/hip_runtime.h>
#include <hip/hip_bf16.h>

typedef unsigned short u16;

#define BATCH 8
#define CIN 512
#define COUT 512
#define SDIM 512
#define RES 64
#define PIX (RES * RES)          // 4096
#define PPIX 4356                // padded 66x66
#define PANEL_E 139392           // PPIX*32 elems per padded B panel

__device__ __constant__ static const float kAffScale  = 0.04419417382415922f;   // 1/sqrt(512)
__device__ __constant__ static const float kConvScale = 0.014731391274719742f;  // 1/sqrt(512*9)
__device__ __constant__ static const float kGain      = 1.4142135623730951f;    // sqrt(2)

typedef __bf16 bf16x8 __attribute__((ext_vector_type(8)));
typedef float  f32x4  __attribute__((ext_vector_type(4)));

// ---------------------------------------------------------------------------
// Kernel 1: style[b][c] = (w[b] . affine_w[c]) * AFF_SCALE + affine_b[c]
// ---------------------------------------------------------------------------
__global__ void style_k(const float* __restrict__ w, const float* __restrict__ aw,
                        const float* __restrict__ ab, float* __restrict__ style) {
  int tid = blockIdx.x * 256 + threadIdx.x;      // 0..4095
  int b = tid >> 9, c = tid & 511;
  const float* wp = w + b * SDIM;
  const float* ap = aw + c * SDIM;
  float s = 0.0f;
  for (int k = 0; k < SDIM; ++k) s += wp[k] * ap[k];
  style[tid] = s * kAffScale + ab[c];
}

// ---------------------------------------------------------------------------
// Kernel 2: cw2[o][i] = sum_t conv_w[o][i][t]^2
// ---------------------------------------------------------------------------
__global__ void cw2_k(const float* __restrict__ cw, float* __restrict__ cw2) {
  int tid = blockIdx.x * 256 + threadIdx.x;      // o*512+i
  const float* p = cw + tid * 9;
  float s = 0.0f;
  #pragma unroll
  for (int t = 0; t < 9; ++t) { float v = p[t]; s += v * v; }
  cw2[tid] = s;
}

// ---------------------------------------------------------------------------
// Kernel 3: fac[b][o] = CONV_SCALE * rsqrt(CONV_SCALE^2 * sum_i style^2*cw2 + 1e-8)
// ---------------------------------------------------------------------------
__global__ void fac_k(const float* __restrict__ style, const float* __restrict__ cw2,
                      float* __restrict__ fac) {
  int wid  = blockIdx.x * 4 + (threadIdx.x >> 6); // 0..4095
  int lane = threadIdx.x & 63;
  int b = wid >> 9, o = wid & 511;
  const float* st = style + b * CIN;
  const float* c2 = cw2 + o * CIN;
  float s = 0.0f;
  for (int i = lane; i < CIN; i += 64) { float sv = st[i]; s += sv * sv * c2[i]; }
  #pragma unroll
  for (int off = 32; off; off >>= 1) s += __shfl_xor(s, off);
  if (lane == 0) {
    float d = rsqrtf(s * kConvScale * kConvScale + 1e-8f);
    fac[wid] = d * kConvScale;
  }
}

// ---------------------------------------------------------------------------
// Kernel 4: wbt[(tap*16+sl)][o][j] = bf16(conv_w[o][sl*32+j][tap])
// ---------------------------------------------------------------------------
__global__ void wcast_k(const float* __restrict__ cw, u16* __restrict__ wbt) {
  int tid = blockIdx.x * 256 + threadIdx.x;      // o*512 + i
  int o = tid >> 9, i = tid & 511;
  const float* p = cw + tid * 9;
  #pragma unroll
  for (int t = 0; t < 9; ++t) {
    __hip_bfloat16 h = __float2bfloat16(p[t]);
    wbt[((size_t)(t * 16 + (i >> 5)) * 512 + o) * 32 + (i & 31)] = *(u16*)&h;
  }
}

// ---------------------------------------------------------------------------
// Kernel 5a: zero the 1-pixel borders of all 128 padded B panels
// ---------------------------------------------------------------------------
__global__ void bz_k(u16* __restrict__ xst) {
  int idx = blockIdx.x * 256 + threadIdx.x;      // panel*4356 + pix
  if (idx >= 128 * PPIX) return;
  int pan = idx / PPIX, pix = idx - pan * PPIX;
  int h = pix / 66, w = pix - h * 66;
  if (h == 0 || h == 65 || w == 0 || w == 65) {
    u16* p = xst + (size_t)pan * PANEL_E + (size_t)pix * 32;
    int4 z = make_int4(0, 0, 0, 0);
    ((int4*)p)[0] = z; ((int4*)p)[1] = z; ((int4*)p)[2] = z; ((int4*)p)[3] = z;
  }
}

// ---------------------------------------------------------------------------
// Kernel 5b: xst[(b*16+sl)][(h+1)*66+(w+1)][j] = bf16(x[b][sl*32+j][h*64+w]*style)
// ---------------------------------------------------------------------------
__global__ void modx_k(const float* __restrict__ x, const float* __restrict__ style,
                       u16* __restrict__ xst) {
  __shared__ float t[64][65];
  int b  = blockIdx.z;
  int it = blockIdx.y * 64;                      // cin tile base
  int pt = blockIdx.x * 64;                      // pixel tile base
  int tp = threadIdx.x & 63;
  int tr = threadIdx.x >> 6;                     // 0..3
  for (int r = tr; r < 64; r += 4) {
    int i = it + r;
    t[r][tp] = x[(b * CIN + i) * PIX + pt + tp] * style[b * CIN + i];
  }
  __syncthreads();
  int i = it + tp;
  size_t pbase = (size_t)(b * 16 + (i >> 5)) * PANEL_E + (i & 31);
  for (int r = tr; r < 64; r += 4) {
    int pix = pt + r, h = pix >> 6, w = pix & 63;
    __hip_bfloat16 hh = __float2bfloat16(t[tp][r]);
    xst[pbase + (size_t)((h + 1) * 66 + (w + 1)) * 32] = *(u16*)&hh;
  }
}

// ---------------------------------------------------------------------------
// Kernel 6: implicit-GEMM conv, cin-block-major K-order (kt = cb*18+tap*2+kh).
// B: 6x66 halo panel per cb staged ONCE into LDS (dbuf, serves all 9 taps).
// A: ring-3 LDS staging (8 KB quanta, D=2 ahead). 144 phases of 32 MFMA,
// 2 barriers/phase, counted lgkm(4)/lgkm(0) + vmcnt(2|8), never 0.
// 8 waves (2Mx4N), wave out 128x64. LDS = 48 KB A-ring + 99 KB B-halo.
// ---------------------------------------------------------------------------
__launch_bounds__(512, 2)
__global__ void gemm_k(const u16* __restrict__ wbt, const u16* __restrict__ xst,
                       const float* __restrict__ fac, const float* __restrict__ noise,
                       const float* __restrict__ nscale_p, const float* __restrict__ bias,
                       float* __restrict__ y) {
  // lds[0..24576)          : A ring, 3 x 8192 elems ([256 rows][32] swizzled)
  // lds[24576..75264)      : B halo, 2 bufs x (2 kh x 396 prow x 32) elems
  __shared__ __align__(16) u16 lds[75264];

  const int tid = threadIdx.x;
  const int bid = blockIdx.x;                    // 0..255
  const int swz = (bid & 7) * 32 + (bid >> 3);   // XCD-chunked (256 % 8 == 0)
  const int mt = swz >> 7;                       // 0..1   cout tile
  const int nt = swz & 127;                      // 0..127 pixel tile
  const int b  = nt >> 4;                        // image
  const int pimg  = (nt & 15) * 256;             // pixel base within image
  const int hbase = pimg >> 6;                   // image row base (0,4,..,60)

  const int lane = tid & 63;
  const int wv = tid >> 6;                       // 0..7
  const int wm = wv >> 2;                        // 0..1  (128 out-rows)
  const int wn = wv & 3;                         // 0..3  (64 out-cols = image row hbase+wn)
  const int l15 = lane & 15, l4 = lane >> 4;
  const int pwn = (wn + 1) * 66 + l15;           // halo prow base for this thread

  // A-read element addresses (per-thread constants), 8 m-fragments
  int aElem[8];
  #pragma unroll
  for (int mi = 0; mi < 8; ++mi) {
    int arow = wm * 128 + mi * 16 + l15;
    aElem[mi] = arow * 32 + ((l4 ^ ((arow >> 1) & 3)) << 3);
  }

  // A staging per-thread constants: chunk c = p*512+tid, row=c>>2, slot=c&3
  const int sgE = ((tid & 3) ^ ((tid >> 3) & 3)) << 3;
  int aoffE[2];
  #pragma unroll
  for (int p = 0; p < 2; ++p)
    aoffE[p] = (mt * 256 + ((p * 512 + tid) >> 2)) * 32 + sgE;

  auto stA = [&](int panel, int ring) {
    const u16* pan = wbt + ((size_t)panel << 14);   // 512*32 elems per panel
    #pragma unroll
    for (int p = 0; p < 2; ++p) {
      __builtin_amdgcn_global_load_lds(
          (const __attribute__((address_space(1))) void*)(pan + aoffE[p]),
          (__attribute__((address_space(3))) void*)(&lds[ring * 8192 + (p * 512 + tid) * 8]),
          16, 0, 0);
    }
  };

  // Stage the 6-row halo (both kh slices) of cin-block cbn: 3168 16B chunks.
  // dest elem = dst0 + c*8 (linear); src = panel(kh) pixel (hbase*66+p), block sg.
  auto stHalo = [&](int cbn) {
    const int dst0 = 24576 + (cbn & 1) * 25344;
    const size_t srcPan = (size_t)(b * 16 + cbn * 2) * PANEL_E + (size_t)(hbase * 66) * 32;
    #pragma unroll
    for (int pass = 0; pass < 6; ++pass) {
      int c = pass * 512 + tid;
      int kh = c >= 1584 ? 1 : 0;
      int r = c - (kh ? 1584 : 0);
      int p = r >> 2;
      int sg = (c & 3) ^ ((p >> 1) & 3);
      const u16* src = xst + srcPan + (size_t)kh * PANEL_E + p * 32 + sg * 8;
      __builtin_amdgcn_global_load_lds(
          (const __attribute__((address_space(1))) void*)src,
          (__attribute__((address_space(3))) void*)(&lds[dst0 + c * 8]), 16, 0, 0);
    }
    if (tid < 96) {                              // tail: chunks 3072..3167 (kh=1)
      int c = 3072 + tid;
      int p = (c - 1584) >> 2;
      int sg = (c & 3) ^ ((p >> 1) & 3);
      const u16* src = xst + srcPan + (size_t)PANEL_E + p * 32 + sg * 8;
      __builtin_amdgcn_global_load_lds(
          (const __attribute__((address_space(1))) void*)src,
          (__attribute__((address_space(3))) void*)(&lds[dst0 + c * 8]), 16, 0, 0);
    }
  };

  f32x4 acc[8][4];
  #pragma unroll
  for (int i = 0; i < 8; ++i)
    #pragma unroll
    for (int j = 0; j < 4; ++j) acc[i][j] = (f32x4){0.f, 0.f, 0.f, 0.f};

  // Prologue: halo(cb0) + A(phase0)->ring0 + A(phase1)->ring1; drain all but A(ph1).
  stHalo(0);
  stA(0, 0);                                     // tap0 cb0 kh0
  stA(1, 1);                                     // tap0 cb0 kh1
  asm volatile("s_waitcnt vmcnt(2)" ::: "memory");
  __builtin_amdgcn_s_barrier();

  // One phase: IDX in [0,18). tap=IDX>>1, kh=IDX&1. Reads ring IDX%3 + halo(cb).
  // Stages A(IDX+2) -> ring (IDX+2)%3; halo(cb+1) at IDX==15.
#define PH(IDX) {                                                              \
    constexpr int tap_ = (IDX) >> 1, kh_ = (IDX) & 1;                          \
    constexpr int rr_ = (IDX) % 3;                                             \
    constexpr int nI_ = (IDX) + 2;                                             \
    constexpr int tapS_ = (nI_ % 18) >> 1, khS_ = (nI_ % 18) & 1;              \
    constexpr int rw_ = nI_ % 3;                                               \
    constexpr int dy_ = tap_ / 3 - 1, dx_ = tap_ % 3 - 1;                      \
    const int sb_ = 24576 + (cb & 1) * 25344 + kh_ * 12672;                    \
    bf16x8 bfr[4], af03[4], af47[4];                                           \
    _Pragma("unroll") for (int ni = 0; ni < 4; ++ni) {                         \
      int prow = pwn + (dy_ * 66 + dx_ + 1 + ni * 16);                         \
      int sl = (l4 ^ ((prow >> 1) & 3)) << 3;                                  \
      bfr[ni] = *(const bf16x8*)&lds[sb_ + prow * 32 + sl];                    \
    }                                                                          \
    _Pragma("unroll") for (int j = 0; j < 4; ++j)                              \
      af03[j] = *(const bf16x8*)&lds[rr_ * 8192 + aElem[j]];                   \
    __builtin_amdgcn_sched_barrier(0);  /* pin: bfr+af03 are oldest 8 lgkm */  \
    _Pragma("unroll") for (int j = 0; j < 4; ++j)                              \
      af47[j] = *(const bf16x8*)&lds[rr_ * 8192 + aElem[4 + j]];               \
    stA(tapS_ * 16 + khS_ + ((nI_ >= 18) ? cbw : cb) * 2, rw_);                \
    if ((IDX) == 15) stHalo(cbw);                                              \
    __builtin_amdgcn_s_barrier();                                              \
    asm volatile("s_waitcnt lgkmcnt(4)" ::: "memory");                         \
    __builtin_amdgcn_sched_barrier(0);                                         \
    __builtin_amdgcn_s_setprio(1);                                             \
    _Pragma("unroll") for (int j = 0; j < 4; ++j)                              \
      _Pragma("unroll") for (int ni = 0; ni < 4; ++ni)                         \
        acc[j][ni] = __builtin_amdgcn_mfma_f32_16x16x32_bf16(af03[j], bfr[ni], acc[j][ni], 0, 0, 0); \
    __builtin_amdgcn_s_setprio(0);                                             \
    asm volatile("s_waitcnt lgkmcnt(0)" ::: "memory");                         \
    __builtin_amdgcn_sched_barrier(0);                                         \
    __builtin_amdgcn_s_setprio(1);                                             \
    _Pragma("unroll") for (int j = 0; j < 4; ++j)                              \
      _Pragma("unroll") for (int ni = 0; ni < 4; ++ni)                         \
        acc[4 + j][ni] = __builtin_amdgcn_mfma_f32_16x16x32_bf16(af47[j], bfr[ni], acc[4 + j][ni], 0, 0, 0); \
    __builtin_amdgcn_s_setprio(0);                                             \
    if ((IDX) == 15 || (IDX) == 16) {                                          \
      asm volatile("s_waitcnt vmcnt(8)" ::: "memory");                         \
    } else {                                                                   \
      asm volatile("s_waitcnt vmcnt(2)" ::: "memory");                         \
    }                                                                          \
    __builtin_amdgcn_s_barrier();                                              \
  }

  for (int cb = 0; cb < 8; ++cb) {
    const int cbw = (cb == 7) ? 0 : cb + 1;
    PH(0)  PH(1)  PH(2)  PH(3)  PH(4)  PH(5)  PH(6)  PH(7)  PH(8)
    PH(9)  PH(10) PH(11) PH(12) PH(13) PH(14) PH(15) PH(16) PH(17)
  }
#undef PH

  // Epilogue: y = lrelu(acc*fac + noise*nscale + bias) * sqrt(2)
  const float ns = nscale_p[0];
  float nz[4];
  #pragma unroll
  for (int ni = 0; ni < 4; ++ni) {
    int pix = pimg + wn * 64 + ni * 16 + l15;
    nz[ni] = noise[b * PIX + pix] * ns;
  }
  #pragma unroll
  for (int mi = 0; mi < 8; ++mi) {
    int o = mt * 256 + wm * 128 + mi * 16 + l4 * 4;
    f32x4 fv = *(const f32x4*)&fac[b * COUT + o];
    f32x4 bv = *(const f32x4*)&bias[o];
    #pragma unroll
    for (int r = 0; r < 4; ++r) {
      float* yp = y + (size_t)(b * COUT + o + r) * PIX + pimg + wn * 64 + l15;
      #pragma unroll
      for (int ni = 0; ni < 4; ++ni) {
        float v = acc[mi][ni][r] * fv[r] + nz[ni] + bv[r];
        v = (v > 0.0f ? v : 0.2f * v) * kGain;
        yp[ni * 16] = v;
      }
    }
  }
}

// ---------------------------------------------------------------------------
extern "C" void kernel_launch(void* const* d_in, const int* in_sizes, int n_in,
                              void* d_out, int out_size, void* d_ws, size_t ws_size,
                              hipStream_t stream) {
  const float* x      = (const float*)d_in[0];
  const float* w      = (const float*)d_in[1];
  const float* noise  = (const float*)d_in[2];
  const float* aff_w  = (const float*)d_in[3];
  const float* aff_b  = (const float*)d_in[4];
  const float* conv_w = (const float*)d_in[5];
  const float* nscale = (const float*)d_in[6];
  const float* bias   = (const float*)d_in[7];
  float* y = (float*)d_out;

  char* ws = (char*)d_ws;
  float* style = (float*)(ws);                          // 16 KB
  float* fac   = (float*)(ws + 16384);                  // 16 KB
  float* cw2   = (float*)(ws + 32768);                  // 1 MB
  u16*   wbt   = (u16*)(ws + 1081600);                  // 4.5 MB panels
  u16*   xst   = (u16*)(ws + 5800192);                  // 128 padded panels, 35.7 MB

  style_k<<<16, 256, 0, stream>>>(w, aff_w, aff_b, style);
  cw2_k<<<1024, 256, 0, stream>>>(conv_w, cw2);
  fac_k<<<1024, 256, 0, stream>>>(style, cw2, fac);
  wcast_k<<<1024, 256, 0, stream>>>(conv_w, wbt);
  bz_k<<<(128 * PPIX + 255) / 256, 256, 0, stream>>>(xst);
  modx_k<<<dim3(64, 8, 8), 256, 0, stream>>>(x, style, xst);
  gemm_k<<<256, 512, 0, stream>>>(wbt, xst, fac, noise, nscale, bias, y);
}